// Round 3
// baseline (651.083 us; speedup 1.0000x reference)
//
#include <hip/hip_runtime.h>

// Problem constants
#define CCH 768
#define NCL 64
#define HWIN 1024                 // 32*32 pixels per batch
#define RES_ELEMS 134217728LL     // 8*64*512*512
#define CODE_ELEMS 6291456LL      // 8*768*32*32
#define CQUADS 1572863LL          // float4 code-copy count: covers out[RES+4 .. RES+4+4*CQUADS)
#define COPY_BLOCKS 1536          // 1536*256 threads * 4 quads >= CQUADS
#define DENSE_BLOCKS 4096         // 8 batches * 512 output rows

// native 4-float vector for nontemporal builtins (HIP float4 is a class type)
typedef float vfloat4 __attribute__((ext_vector_type(4)));

// ---------------------------------------------------------------------------
// k_norm: 64 blocks: L2-normalize cluster row n=blk into nc_t[c][n] (transposed).
// Block 0 thread 0 also writes the odd head/tail scalars (loss=0, code head/tail).
// ---------------------------------------------------------------------------
__global__ __launch_bounds__(256) void k_norm(const float* __restrict__ clusters,
                                              const float* __restrict__ code,
                                              float* __restrict__ nc_t,
                                              float* __restrict__ out)
{
    int tid = threadIdx.x;
    int n = blockIdx.x;
    __shared__ float red[256];
    float v0 = clusters[n * CCH + tid];
    float v1 = clusters[n * CCH + tid + 256];
    float v2 = clusters[n * CCH + tid + 512];
    red[tid] = v0 * v0 + v1 * v1 + v2 * v2;
    __syncthreads();
    for (int off = 128; off > 0; off >>= 1) {
        if (tid < off) red[tid] += red[tid + off];
        __syncthreads();
    }
    float scale = 1.0f / fmaxf(sqrtf(red[0]), 1e-12f);
    nc_t[(tid      ) * NCL + n] = v0 * scale;
    nc_t[(tid + 256) * NCL + n] = v1 * scale;
    nc_t[(tid + 512) * NCL + n] = v2 * scale;
    if (n == 0 && tid == 0) {
        out[0] = 0.0f;                         // loss accumulator
        out[RES_ELEMS + 1] = code[0];          // code-copy head (3 scalars)
        out[RES_ELEMS + 2] = code[1];
        out[RES_ELEMS + 3] = code[2];
        out[RES_ELEMS + CODE_ELEMS] = code[CODE_ELEMS - 1];   // code-copy tail
    }
}

// ---------------------------------------------------------------------------
// k_assign: 256 blocks x 256 thr. Block handles 32 pixels, full C=768.
// Thread = (cg 0..7: 96 ch) x (ng 0..3: 16 clusters) x (pg 0..7: 4 pixels).
// acc[4 px][16 n] in regs; cluster tile (64 ch x 64 n) staged in LDS per chunk.
// Then LDS tree-reduce over cg, per-pixel argmax, loss atomicAdd.
// ---------------------------------------------------------------------------
__global__ __launch_bounds__(256) void k_assign(const float* __restrict__ code,
                                                const float* __restrict__ nc_t,
                                                int* __restrict__ assign,
                                                float* __restrict__ out)
{
    __shared__ float lds_nc[64 * 64];     // 16 KB staging; reused for reduced dots
    __shared__ float lds_red[8 * 2048];   // 64 KB cg-partials
    __shared__ float lds_sq[8 * 32];      // sumsq partials

    int tid = threadIdx.x;
    int blk = blockIdx.x;
    int cg = tid >> 5;
    int ng = (tid >> 3) & 3;
    int pg = tid & 7;
    int b = blk >> 5;
    int pixb = (blk & 31) << 5;
    const float* codeB = code + (size_t)b * CCH * HWIN + pixb + (pg << 2);

    float acc[4][16];
    #pragma unroll
    for (int p = 0; p < 4; ++p)
        #pragma unroll
        for (int q = 0; q < 16; ++q) acc[p][q] = 0.f;
    float sq0 = 0.f, sq1 = 0.f, sq2 = 0.f, sq3 = 0.f;

    for (int k = 0; k < 12; ++k) {
        __syncthreads();
        const float4* src = (const float4*)(nc_t + k * 4096);
        float4* dst = (float4*)lds_nc;
        #pragma unroll
        for (int i = 0; i < 4; ++i) dst[tid + 256 * i] = src[tid + 256 * i];
        __syncthreads();
        #pragma unroll
        for (int m = 0; m < 8; ++m) {
            int ch = k * 64 + cg * 8 + m;
            float4 f = *(const float4*)(codeB + ch * HWIN);
            sq0 += f.x * f.x; sq1 += f.y * f.y; sq2 += f.z * f.z; sq3 += f.w * f.w;
            const float* ncrow = lds_nc + ((cg * 8 + m) << 6) + (ng << 4);
            #pragma unroll
            for (int q = 0; q < 16; ++q) {
                float w = ncrow[q];
                acc[0][q] += f.x * w;
                acc[1][q] += f.y * w;
                acc[2][q] += f.z * w;
                acc[3][q] += f.w * w;
            }
        }
    }

    #pragma unroll
    for (int p = 0; p < 4; ++p) {
        float4* dstp = (float4*)&lds_red[cg * 2048 + (pg * 4 + p) * 64 + ng * 16];
        dstp[0] = make_float4(acc[p][0],  acc[p][1],  acc[p][2],  acc[p][3]);
        dstp[1] = make_float4(acc[p][4],  acc[p][5],  acc[p][6],  acc[p][7]);
        dstp[2] = make_float4(acc[p][8],  acc[p][9],  acc[p][10], acc[p][11]);
        dstp[3] = make_float4(acc[p][12], acc[p][13], acc[p][14], acc[p][15]);
    }
    if (ng == 0) {
        lds_sq[cg * 32 + pg * 4 + 0] = sq0;
        lds_sq[cg * 32 + pg * 4 + 1] = sq1;
        lds_sq[cg * 32 + pg * 4 + 2] = sq2;
        lds_sq[cg * 32 + pg * 4 + 3] = sq3;
    }
    __syncthreads();

    for (int idx = tid; idx < 2048; idx += 256) {
        float s = 0.f;
        #pragma unroll
        for (int c2 = 0; c2 < 8; ++c2) s += lds_red[c2 * 2048 + idx];
        lds_nc[idx] = s;
    }
    __syncthreads();

    if (tid < 32) {
        float ss = 0.f;
        #pragma unroll
        for (int c2 = 0; c2 < 8; ++c2) ss += lds_sq[c2 * 32 + tid];
        float inv = 1.0f / fmaxf(sqrtf(ss), 1e-12f);
        float best = -1e30f; int bi = 0;
        for (int n = 0; n < 64; ++n) {
            float v = lds_nc[tid * 64 + n];
            if (v > best) { best = v; bi = n; }
        }
        assign[blk * 32 + tid] = bi;
        float l = best * inv;
        l += __shfl_down(l, 16);
        l += __shfl_down(l, 8);
        l += __shfl_down(l, 4);
        l += __shfl_down(l, 2);
        l += __shfl_down(l, 1);
        if (tid == 0) atomicAdd(out, -l * (1.0f / 8192.0f));
    }
}

// ---------------------------------------------------------------------------
// k_dense: blocks [0,4096): one block per (batch, output row i). Computes the
// bilinear-upsampled one-hot planes DENSELY (every element written exactly once,
// zero or weight) -> pure streaming stores, no zero-fill pass, no RMW scatter.
// All out stores are NONTEMPORAL (write-once 537 MiB stream; skip L2 pollution).
//   slot s==0   -> scalar j {0,1,2,511} (alignment head/tail of each 512-row)
//   slot 1..127 -> aligned float4 at j = 4s-1
// Blocks [4096, 4096+1536): grid-stride float4 copy of code into the out tail.
// ---------------------------------------------------------------------------
__global__ __launch_bounds__(256) void k_dense(const int* __restrict__ assign,
                                               const float* __restrict__ code,
                                               float* __restrict__ out)
{
    int tid = threadIdx.x;
    int blk = blockIdx.x;

    if (blk >= DENSE_BLOCKS) {
        // ---- code copy: out[1+RES+e] = code[e], aligned-quad region ----
        long long u = (long long)(blk - DENSE_BLOCKS) * 256 + tid;
        #pragma unroll
        for (int k = 0; k < 4; ++k) {
            long long q = u + (long long)k * (COPY_BLOCKS * 256);
            if (q < CQUADS) {
                const float* src = code + 3 + 4 * q;          // src misaligned
                vfloat4 v;
                v.x = __builtin_nontemporal_load(src + 0);
                v.y = __builtin_nontemporal_load(src + 1);
                v.z = __builtin_nontemporal_load(src + 2);
                v.w = __builtin_nontemporal_load(src + 3);
                __builtin_nontemporal_store(v, (vfloat4*)(out + RES_ELEMS + 4 + 4 * q));
            }
        }
        return;
    }

    int b = blk >> 9;        // batch
    int i = blk & 511;       // output row
    __shared__ int   s_r0[32], s_r1[32];
    __shared__ int4  s_ids[128];   // packed corner ids per slot (4 j's each)
    __shared__ float4 s_fj[128];   // fj per j of slot

    // row-level bilinear params (uniform across block)
    float xi = (i + 0.5f) * 0.0625f - 0.5f;
    float fif = floorf(xi);
    int ii = (int)fif;
    float fi = xi - fif;
    int i0 = ii < 0 ? 0 : ii;
    int i1 = (ii + 1) > 31 ? 31 : (ii + 1);

    if (tid < 32) {
        s_r0[tid] = assign[(b << 10) + (i0 << 5) + tid];
        s_r1[tid] = assign[(b << 10) + (i1 << 5) + tid];
    }
    __syncthreads();

    if (tid < 128) {
        int s = tid;
        int4 ids; float4 fj4;
        int jl[4];
        if (s == 0) { jl[0] = 0; jl[1] = 1; jl[2] = 2; jl[3] = 511; }
        else { jl[0] = 4 * s - 1; jl[1] = 4 * s; jl[2] = 4 * s + 1; jl[3] = 4 * s + 2; }
        int pk[4]; float fjv[4];
        #pragma unroll
        for (int k = 0; k < 4; ++k) {
            int j = jl[k];
            float xj = (j + 0.5f) * 0.0625f - 0.5f;
            float fjf = floorf(xj);
            int jj = (int)fjf;
            fjv[k] = xj - fjf;
            int j0 = jj < 0 ? 0 : jj;
            int j1 = (jj + 1) > 31 ? 31 : (jj + 1);
            pk[k] = s_r0[j0] | (s_r0[j1] << 8) | (s_r1[j0] << 16) | (s_r1[j1] << 24);
        }
        ids.x = pk[0]; ids.y = pk[1]; ids.z = pk[2]; ids.w = pk[3];
        fj4.x = fjv[0]; fj4.y = fjv[1]; fj4.z = fjv[2]; fj4.w = fjv[3];
        s_ids[s] = ids;
        s_fj[s] = fj4;
    }
    __syncthreads();

    float fi1 = 1.0f - fi;
    long long rowoff = 1LL + ((long long)b << 24) + ((long long)i << 9);

    #pragma unroll 4
    for (int it = 0; it < 32; ++it) {
        int task = it * 256 + tid;
        int n = task >> 7;
        int s = task & 127;
        int4 p4 = s_ids[s];
        float4 f4 = s_fj[s];
        float v[4];
        int pks[4] = { p4.x, p4.y, p4.z, p4.w };
        float fjs[4] = { f4.x, f4.y, f4.z, f4.w };
        #pragma unroll
        for (int k = 0; k < 4; ++k) {
            int p = pks[k];
            float P = (((p      ) & 255) == n ? fi1 : 0.f)
                    + (((p >> 16) & 255) == n ? fi  : 0.f);
            float Q = (((p >>  8) & 255) == n ? fi1 : 0.f)
                    + (((p >> 24) & 255) == n ? fi  : 0.f);
            v[k] = P + fjs[k] * (Q - P);
        }
        float* rowbase = out + rowoff + ((long long)n << 18);
        if (s == 0) {
            __builtin_nontemporal_store(v[0], rowbase + 0);
            __builtin_nontemporal_store(v[1], rowbase + 1);
            __builtin_nontemporal_store(v[2], rowbase + 2);
            __builtin_nontemporal_store(v[3], rowbase + 511);
        } else {
            vfloat4 vv; vv.x = v[0]; vv.y = v[1]; vv.z = v[2]; vv.w = v[3];
            __builtin_nontemporal_store(vv, (vfloat4*)(rowbase + 4 * s - 1));
        }
    }
}

// ---------------------------------------------------------------------------
extern "C" void kernel_launch(void* const* d_in, const int* in_sizes, int n_in,
                              void* d_out, int out_size, void* d_ws, size_t ws_size,
                              hipStream_t stream)
{
    const float* code     = (const float*)d_in[0];   // [8,768,32,32]
    const float* clusters = (const float*)d_in[1];   // [64,768]
    float* out = (float*)d_out;                      // [loss | resized | code]
    float* nc_t = (float*)d_ws;                      // 768*64 floats, [c][n]
    int* assign = (int*)((char*)d_ws + 196608);      // 8192 ints

    k_norm  <<<NCL,                       256, 0, stream>>>(clusters, code, nc_t, out);
    k_assign<<<256,                       256, 0, stream>>>(code, nc_t, assign, out);
    k_dense <<<DENSE_BLOCKS + COPY_BLOCKS, 256, 0, stream>>>(assign, code, out);
}

// Round 4
// 618.560 us; speedup vs baseline: 1.0526x; 1.0526x over previous
//
#include <hip/hip_runtime.h>

// Problem constants
#define CCH 768
#define NCL 64
#define HWIN 1024                 // 32*32 pixels per batch
#define RES_ELEMS 134217728LL     // 8*64*512*512
#define CODE_ELEMS 6291456LL      // 8*768*32*32
#define CQUADS 1572863LL          // float4 code-copy count
#define COPY_BLOCKS 1536          // 1536*256 threads * 4 quads >= CQUADS
#define DENSE_BLOCKS 2048         // 8 b * 64 n * 4 chunks of 128 rows

// ---------------------------------------------------------------------------
// k_norm: 64 blocks: L2-normalize cluster row n=blk into nc_t[c][n] (transposed).
// Block 0 thread 0 also writes the odd head/tail scalars (loss=0, code head/tail).
// ---------------------------------------------------------------------------
__global__ __launch_bounds__(256) void k_norm(const float* __restrict__ clusters,
                                              const float* __restrict__ code,
                                              float* __restrict__ nc_t,
                                              float* __restrict__ out)
{
    int tid = threadIdx.x;
    int n = blockIdx.x;
    __shared__ float red[256];
    float v0 = clusters[n * CCH + tid];
    float v1 = clusters[n * CCH + tid + 256];
    float v2 = clusters[n * CCH + tid + 512];
    red[tid] = v0 * v0 + v1 * v1 + v2 * v2;
    __syncthreads();
    for (int off = 128; off > 0; off >>= 1) {
        if (tid < off) red[tid] += red[tid + off];
        __syncthreads();
    }
    float scale = 1.0f / fmaxf(sqrtf(red[0]), 1e-12f);
    nc_t[(tid      ) * NCL + n] = v0 * scale;
    nc_t[(tid + 256) * NCL + n] = v1 * scale;
    nc_t[(tid + 512) * NCL + n] = v2 * scale;
    if (n == 0 && tid == 0) {
        out[0] = 0.0f;                         // loss accumulator
        out[RES_ELEMS + 1] = code[0];          // code-copy head (3 scalars)
        out[RES_ELEMS + 2] = code[1];
        out[RES_ELEMS + 3] = code[2];
        out[RES_ELEMS + CODE_ELEMS] = code[CODE_ELEMS - 1];   // code-copy tail
    }
}

// ---------------------------------------------------------------------------
// k_assign: unchanged from the 640 µs baseline.
// ---------------------------------------------------------------------------
__global__ __launch_bounds__(256) void k_assign(const float* __restrict__ code,
                                                const float* __restrict__ nc_t,
                                                int* __restrict__ assign,
                                                float* __restrict__ out)
{
    __shared__ float lds_nc[64 * 64];     // 16 KB staging; reused for reduced dots
    __shared__ float lds_red[8 * 2048];   // 64 KB cg-partials
    __shared__ float lds_sq[8 * 32];      // sumsq partials

    int tid = threadIdx.x;
    int blk = blockIdx.x;
    int cg = tid >> 5;
    int ng = (tid >> 3) & 3;
    int pg = tid & 7;
    int b = blk >> 5;
    int pixb = (blk & 31) << 5;
    const float* codeB = code + (size_t)b * CCH * HWIN + pixb + (pg << 2);

    float acc[4][16];
    #pragma unroll
    for (int p = 0; p < 4; ++p)
        #pragma unroll
        for (int q = 0; q < 16; ++q) acc[p][q] = 0.f;
    float sq0 = 0.f, sq1 = 0.f, sq2 = 0.f, sq3 = 0.f;

    for (int k = 0; k < 12; ++k) {
        __syncthreads();
        const float4* src = (const float4*)(nc_t + k * 4096);
        float4* dst = (float4*)lds_nc;
        #pragma unroll
        for (int i = 0; i < 4; ++i) dst[tid + 256 * i] = src[tid + 256 * i];
        __syncthreads();
        #pragma unroll
        for (int m = 0; m < 8; ++m) {
            int ch = k * 64 + cg * 8 + m;
            float4 f = *(const float4*)(codeB + ch * HWIN);
            sq0 += f.x * f.x; sq1 += f.y * f.y; sq2 += f.z * f.z; sq3 += f.w * f.w;
            const float* ncrow = lds_nc + ((cg * 8 + m) << 6) + (ng << 4);
            #pragma unroll
            for (int q = 0; q < 16; ++q) {
                float w = ncrow[q];
                acc[0][q] += f.x * w;
                acc[1][q] += f.y * w;
                acc[2][q] += f.z * w;
                acc[3][q] += f.w * w;
            }
        }
    }

    #pragma unroll
    for (int p = 0; p < 4; ++p) {
        float4* dstp = (float4*)&lds_red[cg * 2048 + (pg * 4 + p) * 64 + ng * 16];
        dstp[0] = make_float4(acc[p][0],  acc[p][1],  acc[p][2],  acc[p][3]);
        dstp[1] = make_float4(acc[p][4],  acc[p][5],  acc[p][6],  acc[p][7]);
        dstp[2] = make_float4(acc[p][8],  acc[p][9],  acc[p][10], acc[p][11]);
        dstp[3] = make_float4(acc[p][12], acc[p][13], acc[p][14], acc[p][15]);
    }
    if (ng == 0) {
        lds_sq[cg * 32 + pg * 4 + 0] = sq0;
        lds_sq[cg * 32 + pg * 4 + 1] = sq1;
        lds_sq[cg * 32 + pg * 4 + 2] = sq2;
        lds_sq[cg * 32 + pg * 4 + 3] = sq3;
    }
    __syncthreads();

    for (int idx = tid; idx < 2048; idx += 256) {
        float s = 0.f;
        #pragma unroll
        for (int c2 = 0; c2 < 8; ++c2) s += lds_red[c2 * 2048 + idx];
        lds_nc[idx] = s;
    }
    __syncthreads();

    if (tid < 32) {
        float ss = 0.f;
        #pragma unroll
        for (int c2 = 0; c2 < 8; ++c2) ss += lds_sq[c2 * 32 + tid];
        float inv = 1.0f / fmaxf(sqrtf(ss), 1e-12f);
        float best = -1e30f; int bi = 0;
        for (int n = 0; n < 64; ++n) {
            float v = lds_nc[tid * 64 + n];
            if (v > best) { best = v; bi = n; }
        }
        assign[blk * 32 + tid] = bi;
        float l = best * inv;
        l += __shfl_down(l, 16);
        l += __shfl_down(l, 8);
        l += __shfl_down(l, 4);
        l += __shfl_down(l, 2);
        l += __shfl_down(l, 1);
        if (tid == 0) atomicAdd(out, -l * (1.0f / 8192.0f));
    }
}

// ---------------------------------------------------------------------------
// k_dense (REWRITE): blocks [0,2048): block = (b, n, 128-row chunk) -> writes a
// CONTIGUOUS 256 KB chunk of one plane (linear global sweep, memset-like).
// One-hot test via per-input-row 32-bit bitmasks (assign[row][j]==n), built
// with __ballot; inner loop = 2 uniform LDS reads + bit-extract lerp per quad.
//   slot s==0   -> scalar j {0,1,2,511};  slot 1..127 -> aligned quad at 4s-1
// Blocks [2048, 2048+1536): grid-stride float4 copy of code into the out tail.
// ---------------------------------------------------------------------------
__global__ __launch_bounds__(256) void k_dense(const int* __restrict__ assign,
                                               const float* __restrict__ code,
                                               float* __restrict__ out)
{
    int tid = threadIdx.x;
    int blk = blockIdx.x;

    if (blk >= DENSE_BLOCKS) {
        // ---- code copy: out[1+RES+e] = code[e], aligned-quad region ----
        long long u = (long long)(blk - DENSE_BLOCKS) * 256 + tid;
        #pragma unroll
        for (int k = 0; k < 4; ++k) {
            long long q = u + (long long)k * (COPY_BLOCKS * 256);
            if (q < CQUADS) {
                const float* src = code + 3 + 4 * q;          // src misaligned
                float4 v = make_float4(src[0], src[1], src[2], src[3]);
                *(float4*)(out + RES_ELEMS + 4 + 4 * q) = v;  // dst aligned
            }
        }
        return;
    }

    int b =  blk >> 8;          // batch 0..7
    int n = (blk >> 2) & 63;    // plane 0..63
    int c =  blk & 3;           // row-chunk 0..3
    int I0 = c << 7;            // first output row of chunk (128 rows)
    int rbase = (I0 >> 4) - 1;  // first (unclamped) input row referenced

    __shared__ unsigned s_mask[10];   // per-input-row one-hot bitmaps for n
    __shared__ int4   s_jj[128];      // packed j0|j1<<8 per j of slot
    __shared__ float4 s_fj[128];      // fj per j of slot

    int lane = tid & 63;
    int w = tid >> 6;

    // ---- bitmask build: rows 0..7 by waves 0..3; rows 8..9 by wave 0 ----
    {
        int r = (w << 1) + (lane >> 5);
        int ir = rbase + r; ir = ir < 0 ? 0 : (ir > 31 ? 31 : ir);
        bool pred = assign[(b << 10) + (ir << 5) + (lane & 31)] == n;
        unsigned long long m = __ballot(pred);
        if (lane == 0) { s_mask[(w << 1)] = (unsigned)m; s_mask[(w << 1) + 1] = (unsigned)(m >> 32); }
    }
    if (w == 0) {
        int r = 8 + (lane >> 5);
        int ir = rbase + r; ir = ir < 0 ? 0 : (ir > 31 ? 31 : ir);
        bool pred = assign[(b << 10) + (ir << 5) + (lane & 31)] == n;
        unsigned long long m = __ballot(pred);
        if (lane == 0) { s_mask[8] = (unsigned)m; s_mask[9] = (unsigned)(m >> 32); }
    }

    // ---- per-slot j tables ----
    if (tid < 128) {
        int s = tid;
        int jl[4];
        if (s == 0) { jl[0] = 0; jl[1] = 1; jl[2] = 2; jl[3] = 511; }
        else { jl[0] = 4 * s - 1; jl[1] = 4 * s; jl[2] = 4 * s + 1; jl[3] = 4 * s + 2; }
        int pj[4]; float fjv[4];
        #pragma unroll
        for (int k = 0; k < 4; ++k) {
            int j = jl[k];
            float xj = (j + 0.5f) * 0.0625f - 0.5f;
            float fjf = floorf(xj);
            int jj = (int)fjf;
            fjv[k] = xj - fjf;
            int j0 = jj < 0 ? 0 : jj;
            int j1 = (jj + 1) > 31 ? 31 : (jj + 1);
            pj[k] = j0 | (j1 << 8);
        }
        s_jj[s] = make_int4(pj[0], pj[1], pj[2], pj[3]);
        s_fj[s] = make_float4(fjv[0], fjv[1], fjv[2], fjv[3]);
    }
    __syncthreads();

    int rr = tid >> 7;          // which of the 2 rows per iteration
    int s  = tid & 127;         // column slot
    int4   pj4 = s_jj[s];       // hoisted: per-thread constants
    float4 fj4 = s_fj[s];
    int   j0a[4] = { pj4.x & 255, pj4.y & 255, pj4.z & 255, pj4.w & 255 };
    int   j1a[4] = { pj4.x >> 8,  pj4.y >> 8,  pj4.z >> 8,  pj4.w >> 8 };
    float fja[4] = { fj4.x, fj4.y, fj4.z, fj4.w };

    long long planebase = 1LL + ((long long)b << 24) + ((long long)n << 18);

    for (int r2 = 0; r2 < 64; ++r2) {
        int i = I0 + (r2 << 1) + rr;
        float xi = (i + 0.5f) * 0.0625f - 0.5f;
        float fif = floorf(xi);
        int ii = (int)fif;
        float fi = xi - fif;
        float fi1 = 1.0f - fi;
        unsigned m0 = s_mask[ii - rbase];        // uniform across row's threads
        unsigned m1 = s_mask[ii - rbase + 1];
        float v[4];
        #pragma unroll
        for (int k = 0; k < 4; ++k) {
            float b00 = (float)((m0 >> j0a[k]) & 1u);
            float b01 = (float)((m0 >> j1a[k]) & 1u);
            float b10 = (float)((m1 >> j0a[k]) & 1u);
            float b11 = (float)((m1 >> j1a[k]) & 1u);
            float P = fi1 * b00 + fi * b10;
            float Q = fi1 * b01 + fi * b11;
            v[k] = P + fja[k] * (Q - P);
        }
        float* rowbase = out + planebase + ((long long)i << 9);
        if (s == 0) {
            rowbase[0] = v[0]; rowbase[1] = v[1]; rowbase[2] = v[2]; rowbase[511] = v[3];
        } else {
            *(float4*)(rowbase + 4 * s - 1) = make_float4(v[0], v[1], v[2], v[3]);
        }
    }
}

// ---------------------------------------------------------------------------
extern "C" void kernel_launch(void* const* d_in, const int* in_sizes, int n_in,
                              void* d_out, int out_size, void* d_ws, size_t ws_size,
                              hipStream_t stream)
{
    const float* code     = (const float*)d_in[0];   // [8,768,32,32]
    const float* clusters = (const float*)d_in[1];   // [64,768]
    float* out = (float*)d_out;                      // [loss | resized | code]
    float* nc_t = (float*)d_ws;                      // 768*64 floats, [c][n]
    int* assign = (int*)((char*)d_ws + 196608);      // 8192 ints

    k_norm  <<<NCL,                        256, 0, stream>>>(clusters, code, nc_t, out);
    k_assign<<<256,                        256, 0, stream>>>(code, nc_t, assign, out);
    k_dense <<<DENSE_BLOCKS + COPY_BLOCKS, 256, 0, stream>>>(assign, code, out);
}